// Round 6
// baseline (715.920 us; speedup 1.0000x reference)
//
#include <hip/hip_runtime.h>
#include <cmath>

namespace {

typedef unsigned short u16;
typedef unsigned int u32;
using short8  = __attribute__((ext_vector_type(8))) short;
using float4v = __attribute__((ext_vector_type(4))) float;

// ---- ws layout (u16 units) ----
constexpr size_t MB_HI   = 0;                      // [3][26][16][64][8]
constexpr size_t MB_LO   = 638976;
constexpr size_t L0_HI   = 1277952;                // [2][16][64][8]
constexpr size_t L0_LO   = L0_HI + 16384;
constexpr size_t ENV_HI  = L0_LO + 16384;          // [8][8][64][8]
constexpr size_t ENV_LO  = ENV_HI + 32768;
constexpr size_t TWOB_HI = ENV_LO + 32768;         // [4][2][64][8]
constexpr size_t TWOB_LO = TWOB_HI + 4096;

__device__ __forceinline__ u16 f2bf(float f) {
    u32 u = __float_as_uint(f);
    u += 0x7FFFu + ((u >> 16) & 1u);
    return (u16)(u >> 16);
}
__device__ __forceinline__ float bf2f(u16 h) {
    return __uint_as_float(((u32)h) << 16);
}
__device__ __forceinline__ float fast_tanh(float x) {
    float e = __expf(-2.f * fabsf(x));
    float t = (1.f - e) * __builtin_amdgcn_rcpf(1.f + e);
    return copysignf(t, x);
}

// ---------------- prep kernels: weights -> bf16 hi/lo MFMA B-fragments ----------------
__global__ void k_prep_main(const float* __restrict__ vw, u16* __restrict__ hi, u16* __restrict__ lo) {
    int id = blockIdx.x * 256 + threadIdx.x;          // 3*26*16*512
    int l = id / 212992, rem = id % 212992;
    int ks = rem >> 13;
    int r2 = rem & 8191;
    int nt = r2 >> 9, lane = (r2 >> 3) & 63, j = r2 & 7;
    int n = nt * 16 + (lane & 15);
    int f = ks * 32 + ((lane >> 4) << 3) + j;
    float w = vw[(size_t)(l * 256 + n) * 832 + f];
    u16 h = f2bf(w);
    hi[id] = h; lo[id] = f2bf(w - bf2f(h));
}
__global__ void k_prep_l0(const float* __restrict__ v0w, u16* __restrict__ hi, u16* __restrict__ lo) {
    int id = blockIdx.x * 256 + threadIdx.x;          // 2*16*512
    int ks = id >> 13;
    int r2 = id & 8191;
    int nt = r2 >> 9, lane = (r2 >> 3) & 63, j = r2 & 7;
    int n = nt * 16 + (lane & 15);
    int f = ks * 32 + ((lane >> 4) << 3) + j;
    float w = (f < 56) ? v0w[n * 56 + f] : 0.f;
    u16 h = f2bf(w);
    hi[id] = h; lo[id] = f2bf(w - bf2f(h));
}
__global__ void k_prep_env(const float* __restrict__ ew, u16* __restrict__ hi, u16* __restrict__ lo) {
    int id = blockIdx.x * 256 + threadIdx.x;          // 8*8*512
    int ks = id >> 12;
    int r2 = id & 4095;
    int nt = r2 >> 9, lane = (r2 >> 3) & 63, j = r2 & 7;
    int n = nt * 16 + (lane & 15);
    int f = ks * 32 + ((lane >> 4) << 3) + j;
    float w = ew[(size_t)(((n >> 3) * 16) + (n & 7)) * 256 + f];
    u16 h = f2bf(w);
    hi[id] = h; lo[id] = f2bf(w - bf2f(h));
}
// two-stream weights: [layer][nt][lane][j]; B[k][n]=Ww[n][k]; layer0 K padded 4->32
__global__ void k_prep_two(const float* __restrict__ w0w, const float* __restrict__ ww,
                           u16* __restrict__ hi, u16* __restrict__ lo) {
    int id = blockIdx.x * 256 + threadIdx.x;          // 4*2*512 = 4096
    int l = id >> 10, r = id & 1023;
    int nt = r >> 9, lane = (r >> 3) & 63, j = r & 7;
    int n = nt * 16 + (lane & 15);
    int f = ((lane >> 4) << 3) + j;
    float w;
    if (l == 0) w = (f < 4) ? w0w[n * 4 + f] : 0.f;
    else        w = ww[(size_t)(((l - 1) * 32) + n) * 32 + f];
    u16 h = f2bf(w);
    hi[id] = h; lo[id] = f2bf(w - bf2f(h));
}

// ---------------- fused per-walker layer ----------------
// one-GEMM K-layout: [0,256) one | [256,512) g1u | [512,768) g1d | [768,800) g2u | [800,832) g2d
template <bool L0, bool RES, bool LAST>
__device__ __forceinline__ void layer_run(
    int t, float (&prev)[4][4], short8 (&twoA)[2][4],
    u16 (*stateF)[32][16][8], u16 (*g2F)[8][16][8], u16 (*g1F)[2][8][4][8],
    float (*twoS)[36],                               // this wave's 16x36 scratch
    const u16* __restrict__ Bhi, const u16* __restrict__ Blo,
    const u16* __restrict__ TBhi, const u16* __restrict__ TBlo,
    const float* __restrict__ bvp, const float* __restrict__ bwp)
{
    const int lane = t & 63, wv = t >> 6, quad = lane >> 4, l16 = lane & 15;
    float4v acc[4];
    #pragma unroll
    for (int q = 0; q < 4; ++q) acc[q] = (float4v){0.f, 0.f, 0.f, 0.f};

    const size_t wb0 = (size_t)(wv * 4) * 512 + (size_t)lane * 8;

    auto mfma_step = [&](int ks, short8 Ah, short8 Al) {
        const u16* bh = Bhi + wb0 + (size_t)ks * 8192;
        const u16* bl = Blo + wb0 + (size_t)ks * 8192;
        #pragma unroll
        for (int q = 0; q < 4; ++q) {
            short8 Wh = *(const short8*)(bh + q * 512);
            short8 Wl = *(const short8*)(bl + q * 512);
            acc[q] = __builtin_amdgcn_mfma_f32_16x16x32_bf16(Ah, Wh, acc[q], 0, 0, 0);
            acc[q] = __builtin_amdgcn_mfma_f32_16x16x32_bf16(Al, Wh, acc[q], 0, 0, 0);
            acc[q] = __builtin_amdgcn_mfma_f32_16x16x32_bf16(Ah, Wl, acc[q], 0, 0, 0);
        }
    };

    if (L0) {
        #pragma unroll
        for (int ks = 0; ks < 2; ++ks) {
            short8 Ah = *(const short8*)&g2F[0][ks * 4 + quad][l16][0];
            short8 Al = *(const short8*)&g2F[1][ks * 4 + quad][l16][0];
            mfma_step(ks, Ah, Al);
        }
    } else {
        #pragma unroll 2
        for (int ks = 0; ks < 8; ++ks) {        // one-part from state frags
            short8 Ah = *(const short8*)&stateF[0][ks * 4 + quad][l16][0];
            short8 Al = *(const short8*)&stateF[1][ks * 4 + quad][l16][0];
            mfma_step(ks, Ah, Al);
        }
        #pragma unroll 4
        for (int ks = 8; ks < 24; ++ks) {       // g1-part: broadcast frags from LDS
            const int ud = (ks < 16) ? 0 : 1;
            const int kg = (ks - 8) & 7;
            short8 Ah = *(const short8*)&g1F[0][ud][kg][quad][0];
            short8 Al = *(const short8*)&g1F[1][ud][kg][quad][0];
            mfma_step(ks, Ah, Al);
        }
        #pragma unroll
        for (int ks = 24; ks < 26; ++ks) {      // g2-part
            short8 Ah = *(const short8*)&g2F[0][(ks - 24) * 4 + quad][l16][0];
            short8 Al = *(const short8*)&g2F[1][(ks - 24) * 4 + quad][l16][0];
            mfma_step(ks, Ah, Al);
        }
    }

    // ---- two-stream GEMM: wave -> tiles it = wv*4+mt; A from registers ----
    float4v tac[4][2];
    #pragma unroll
    for (int mt = 0; mt < 4; ++mt)
        #pragma unroll
        for (int nt = 0; nt < 2; ++nt) tac[mt][nt] = (float4v){0.f, 0.f, 0.f, 0.f};
    {
        #pragma unroll
        for (int nt = 0; nt < 2; ++nt) {
            short8 TWh = *(const short8*)(TBhi + nt * 512 + (size_t)lane * 8);
            short8 TWl = *(const short8*)(TBlo + nt * 512 + (size_t)lane * 8);
            #pragma unroll
            for (int mt = 0; mt < 4; ++mt) {
                tac[mt][nt] = __builtin_amdgcn_mfma_f32_16x16x32_bf16(twoA[0][mt], TWh, tac[mt][nt], 0, 0, 0);
                tac[mt][nt] = __builtin_amdgcn_mfma_f32_16x16x32_bf16(twoA[1][mt], TWh, tac[mt][nt], 0, 0, 0);
                tac[mt][nt] = __builtin_amdgcn_mfma_f32_16x16x32_bf16(twoA[0][mt], TWl, tac[mt][nt], 0, 0, 0);
            }
        }
    }
    __syncthreads();   // all LDS A-source reads complete

    // ---- epilogue-one: bias+tanh+residual (regs), g1 means -> g1F, state frags ----
    #pragma unroll
    for (int q = 0; q < 4; ++q) {
        const int n = (wv * 4 + q) * 16 + l16;
        const float bvv = bvp[n];
        #pragma unroll
        for (int r = 0; r < 4; ++r) {
            float v = fast_tanh(acc[q][r] + bvv);
            if (RES) v += prev[q][r];
            prev[q][r] = v;
        }
        if (!LAST) {
            float su = 0.f, sd = 0.f;
            #pragma unroll
            for (int r = 0; r < 4; ++r) { if (quad < 2) su += prev[q][r]; else sd += prev[q][r]; }
            su += __shfl_xor(su, 16); su += __shfl_xor(su, 32);
            sd += __shfl_xor(sd, 16); sd += __shfl_xor(sd, 32);
            if (quad == 0) {
                const int kg = n >> 5, qd = (n >> 3) & 3, jj = n & 7;
                float mu = su * 0.125f, md = sd * 0.125f;
                u16 hu = f2bf(mu), hd = f2bf(md);
                g1F[0][0][kg][qd][jj] = hu; g1F[1][0][kg][qd][jj] = f2bf(mu - bf2f(hu));
                g1F[0][1][kg][qd][jj] = hd; g1F[1][1][kg][qd][jj] = f2bf(md - bf2f(hd));
            }
        }
        const int ko = n >> 3, jj = n & 7;
        #pragma unroll
        for (int r = 0; r < 4; ++r) {
            const int m = quad * 4 + r;
            u16 h = f2bf(prev[q][r]);
            stateF[0][ko][m][jj] = h;
            stateF[1][ko][m][jj] = f2bf(prev[q][r] - bf2f(h));
        }
    }

    // ---- epilogue-two: tanh -> wave scratch (C layout) -> A-regs (+residual),
    //      g2 means from new A-values ----
    if (!LAST) {
        #pragma unroll
        for (int mt = 0; mt < 4; ++mt) {
            const int it = wv * 4 + mt;
            #pragma unroll
            for (int nt = 0; nt < 2; ++nt) {
                const int c = nt * 16 + l16;
                const float bwv = bwp[c];
                #pragma unroll
                for (int r = 0; r < 4; ++r)
                    twoS[quad * 4 + r][c] = fast_tanh(tac[mt][nt][r] + bwv);
            }
            // A-layout read: row l16, channels quad*8..+7 (wave-private, in-order LDS)
            float4 ra = *(const float4*)&twoS[l16][quad * 8];
            float4 rb = *(const float4*)&twoS[l16][quad * 8 + 4];
            float nv[8] = {ra.x, ra.y, ra.z, ra.w, rb.x, rb.y, rb.z, rb.w};
            #pragma unroll
            for (int j2 = 0; j2 < 8; ++j2) {
                float v = nv[j2];
                if (RES) v += bf2f((u16)twoA[0][mt][j2]) + bf2f((u16)twoA[1][mt][j2]);
                nv[j2] = v;
                u16 h = f2bf(v);
                twoA[0][mt][j2] = (short)h;
                twoA[1][mt][j2] = (short)f2bf(v - bf2f(h));
            }
            // g2 means: reduce over pairs (l16 octets)
            #pragma unroll
            for (int j2 = 0; j2 < 8; ++j2) {
                float s = nv[j2];
                s += __shfl_xor(s, 1); s += __shfl_xor(s, 2); s += __shfl_xor(s, 4);
                nv[j2] = s * 0.125f;
            }
            if (l16 == 0 || l16 == 8) {
                const int base = (l16 == 0) ? 0 : 4;
                #pragma unroll
                for (int j2 = 0; j2 < 8; ++j2) {
                    u16 h = f2bf(nv[j2]);
                    g2F[0][base + quad][it][j2] = h;
                    g2F[1][base + quad][it][j2] = f2bf(nv[j2] - bf2f(h));
                }
            }
        }
    }
    __syncthreads();
}

__global__ __launch_bounds__(256, 4) void ferminet_kernel(
    const float* __restrict__ x,
    const float* __restrict__ nuc,
    const float* __restrict__ v0_b,
    const float* __restrict__ v_b,
    const float* __restrict__ w0_b,
    const float* __restrict__ w_b,
    const float* __restrict__ env_g,
    const float* __restrict__ sigma,
    const float* __restrict__ pi_,
    const u16* __restrict__ wsB,
    float* __restrict__ out)
{
    __shared__ u16  stateF[2][32][16][8];   // 16 KB; psi aliases after layers
    __shared__ u16  g2F[2][8][16][8];       // 4 KB; l0 one-A aliases
    __shared__ u16  g1F[2][2][8][4][8];     // 2 KB
    __shared__ float twoS[4][16][36];       // 9 KB per-wave transpose scratch
    __shared__ float xs[48];
    __shared__ float rs[64];
    __shared__ float dets[2][16];
    float* psi = (float*)&stateF[0][0][0][0];   // [2][16][8][8] fp32

    const int t = threadIdx.x;
    const int b = blockIdx.x;
    const int lane = t & 63, wv = t >> 6, quad = lane >> 4, l16 = lane & 15;

    if (t < 48) xs[t] = x[(size_t)b * 48 + t];
    // zero l0A pad octet (koct 7: k 56..63)
    if (t >= 128 && t < 192) ((u32*)&g2F[0][7][0][0])[t - 128] = 0u;
    if (t >= 192 && t < 256) ((u32*)&g2F[1][7][0][0])[t - 192] = 0u;
    __syncthreads();

    // ---- init: one0 features + r + g1u0/g1d0 (threads 0..63) ----
    if (t < 64) {
        int n = t >> 2, m = t & 3;
        float ox = xs[n * 3 + 0] - nuc[m * 3 + 0];
        float oy = xs[n * 3 + 1] - nuc[m * 3 + 1];
        float oz = xs[n * 3 + 2] - nuc[m * 3 + 2];
        float d = sqrtf(ox * ox + oy * oy + oz * oz);
        rs[n * 4 + m] = d;
        float v[4] = {ox, oy, oz, d};
        #pragma unroll
        for (int c = 0; c < 4; ++c) {
            int k = m * 4 + c;
            u16 h = f2bf(v[c]);
            g2F[0][k >> 3][n][k & 7] = h;
            g2F[1][k >> 3][n][k & 7] = f2bf(v[c] - bf2f(h));
        }
        #pragma unroll
        for (int c = 0; c < 4; ++c) {
            float s = v[c];
            s += __shfl_xor(s, 4); s += __shfl_xor(s, 8); s += __shfl_xor(s, 16);
            if ((n & 7) == 0) {
                float mn = s * 0.125f;
                int k = 16 + (n >> 3) * 16 + m * 4 + c;
                u16 h = f2bf(mn);
                u16 lo = f2bf(mn - bf2f(h));
                #pragma unroll
                for (int mm = 0; mm < 16; ++mm) {
                    g2F[0][k >> 3][mm][k & 7] = h;
                    g2F[1][k >> 3][mm][k & 7] = lo;
                }
            }
        }
    }
    // ---- init: g2u0/g2d0 means for l0A (threads 0..127: t = i*8 + ud*4 + c) ----
    if (t < 128) {
        int i = t >> 3, ud = (t >> 2) & 1, c = t & 3;
        float s = 0.f;
        #pragma unroll
        for (int jo = 0; jo < 8; ++jo) {
            int j = ud * 8 + jo;
            float dx = xs[j * 3 + 0] - xs[i * 3 + 0];
            float dy = xs[j * 3 + 1] - xs[i * 3 + 1];
            float dz = xs[j * 3 + 2] - xs[i * 3 + 2];
            float v;
            if (c == 0) v = dx;
            else if (c == 1) v = dy;
            else if (c == 2) v = dz;
            else { float s2 = dx * dx + dy * dy + dz * dz; v = (s2 > 0.f) ? sqrtf(s2) : 0.f; }
            s += v;
        }
        float mn = s * 0.125f;
        int k = 48 + ud * 4 + c;
        u16 h = f2bf(mn);
        g2F[0][6][i][k & 7] = h;
        g2F[1][6][i][k & 7] = f2bf(mn - bf2f(h));
    }
    // ---- init two0 A-fragments in registers: lane (quad,l16) <- pair (it, l16) ----
    short8 twoA[2][4];
    {
        short8 z8 = {0, 0, 0, 0, 0, 0, 0, 0};
        #pragma unroll
        for (int mt = 0; mt < 4; ++mt) { twoA[0][mt] = z8; twoA[1][mt] = z8; }
        if (quad == 0) {
            #pragma unroll
            for (int mt = 0; mt < 4; ++mt) {
                const int it = wv * 4 + mt;
                float dx = xs[l16 * 3 + 0] - xs[it * 3 + 0];
                float dy = xs[l16 * 3 + 1] - xs[it * 3 + 1];
                float dz = xs[l16 * 3 + 2] - xs[it * 3 + 2];
                float s2 = dx * dx + dy * dy + dz * dz;
                float nr = (s2 > 0.f) ? sqrtf(s2) : 0.f;
                float v[4] = {dx, dy, dz, nr};
                #pragma unroll
                for (int c = 0; c < 4; ++c) {
                    u16 h = f2bf(v[c]);
                    twoA[0][mt][c] = (short)h;
                    twoA[1][mt][c] = (short)f2bf(v[c] - bf2f(h));
                }
            }
        }
    }
    __syncthreads();

    // ---- 4 layers ----
    float prev[4][4];
    layer_run<true,  false, false>(t, prev, twoA, stateF, g2F, g1F, twoS[wv],
        wsB + L0_HI, wsB + L0_LO, wsB + TWOB_HI, wsB + TWOB_LO, v0_b, w0_b);
    layer_run<false, true,  false>(t, prev, twoA, stateF, g2F, g1F, twoS[wv],
        wsB + MB_HI + 0 * 212992, wsB + MB_LO + 0 * 212992,
        wsB + TWOB_HI + 1024, wsB + TWOB_LO + 1024, v_b + 0 * 256, w_b + 0 * 32);
    layer_run<false, true,  false>(t, prev, twoA, stateF, g2F, g1F, twoS[wv],
        wsB + MB_HI + 1 * 212992, wsB + MB_LO + 1 * 212992,
        wsB + TWOB_HI + 2048, wsB + TWOB_LO + 2048, v_b + 1 * 256, w_b + 1 * 32);
    layer_run<false, true,  true >(t, prev, twoA, stateF, g2F, g1F, twoS[wv],
        wsB + MB_HI + 2 * 212992, wsB + MB_LO + 2 * 212992,
        wsB + TWOB_HI + 3072, wsB + TWOB_LO + 3072, v_b + 2 * 256, w_b + 2 * 32);

    // ---- envelope GEMM: K=256, N=128 (wave -> 2 ntiles) ----
    {
        float4v ac2[2];
        ac2[0] = (float4v){0.f, 0.f, 0.f, 0.f};
        ac2[1] = (float4v){0.f, 0.f, 0.f, 0.f};
        const size_t wb0 = (size_t)(wv * 2) * 512 + (size_t)lane * 8;
        const u16* Eh = wsB + ENV_HI;
        const u16* El = wsB + ENV_LO;
        #pragma unroll 2
        for (int ks = 0; ks < 8; ++ks) {
            short8 Ah = *(const short8*)&stateF[0][ks * 4 + quad][l16][0];
            short8 Al = *(const short8*)&stateF[1][ks * 4 + quad][l16][0];
            const u16* bh = Eh + wb0 + (size_t)ks * 4096;
            const u16* bl = El + wb0 + (size_t)ks * 4096;
            #pragma unroll
            for (int q = 0; q < 2; ++q) {
                short8 Wh = *(const short8*)(bh + q * 512);
                short8 Wl = *(const short8*)(bl + q * 512);
                ac2[q] = __builtin_amdgcn_mfma_f32_16x16x32_bf16(Ah, Wh, ac2[q], 0, 0, 0);
                ac2[q] = __builtin_amdgcn_mfma_f32_16x16x32_bf16(Al, Wh, ac2[q], 0, 0, 0);
                ac2[q] = __builtin_amdgcn_mfma_f32_16x16x32_bf16(Ah, Wl, ac2[q], 0, 0, 0);
            }
        }
        float vals[2][4];
        int kk[2], ii[2];
        #pragma unroll
        for (int q = 0; q < 2; ++q) {
            const int n = (wv * 2 + q) * 16 + l16;
            const int k = n >> 3, i = n & 7, kif = k * 16 + i;
            kk[q] = k; ii[q] = i;
            const float lc = 256.f * env_g[kif];
            const float4 pw4 = *(const float4*)&pi_[(size_t)kif * 4];
            const float4 sg4 = *(const float4*)&sigma[(size_t)kif * 4];
            const float sg[4] = {fabsf(sg4.x), fabsf(sg4.y), fabsf(sg4.z), fabsf(sg4.w)};
            const float pw[4] = {pw4.x, pw4.y, pw4.z, pw4.w};
            #pragma unroll
            for (int r = 0; r < 4; ++r) {
                const int je = quad * 4 + r;
                float E = 0.f;
                #pragma unroll
                for (int m = 0; m < 4; ++m) E += pw[m] * __expf(-sg[m] * rs[je * 4 + m]);
                vals[q][r] = (ac2[q][r] + lc) * E;
            }
        }
        __syncthreads();   // state-frag reads complete before psi overwrite
        #pragma unroll
        for (int q = 0; q < 2; ++q) {
            #pragma unroll
            for (int r = 0; r < 4; ++r) {
                const int je = quad * 4 + r;
                const int s = je >> 3, j = je & 7;
                psi[((s * 16 + kk[q]) * 8 + ii[q]) * 8 + j] = vals[q][r];
            }
        }
    }
    __syncthreads();

    // ---- 32 8x8 determinants ----
    if (t < 32) {
        int s = t >> 4, k = t & 15;
        const float* src = psi + (s * 16 + k) * 64;
        float m[8][8];
        #pragma unroll
        for (int i = 0; i < 8; ++i)
            #pragma unroll
            for (int j = 0; j < 8; ++j) m[i][j] = src[i * 8 + j];
        float det = 1.f;
        #pragma unroll
        for (int c = 0; c < 8; ++c) {
            #pragma unroll
            for (int r = c + 1; r < 8; ++r) {
                if (fabsf(m[r][c]) > fabsf(m[c][c])) {
                    det = -det;
                    #pragma unroll
                    for (int j = 0; j < 8; ++j) {
                        float tmp = m[c][j]; m[c][j] = m[r][j]; m[r][j] = tmp;
                    }
                }
            }
            float piv = m[c][c];
            det *= piv;
            if (piv != 0.f) {
                float inv = 1.f / piv;
                #pragma unroll
                for (int r = c + 1; r < 8; ++r) {
                    float fac = m[r][c] * inv;
                    #pragma unroll
                    for (int j = c; j < 8; ++j) m[r][j] -= fac * m[c][j];
                }
            }
        }
        dets[s][k] = det;
    }
    __syncthreads();

    if (t == 0) {
        float s = 0.f;
        #pragma unroll
        for (int k = 0; k < 16; ++k) s += dets[0][k] * dets[1][k];
        out[b] = s;
    }
}

} // namespace

extern "C" void kernel_launch(void* const* d_in, const int* in_sizes, int n_in,
                              void* d_out, int out_size, void* d_ws, size_t ws_size,
                              hipStream_t stream) {
    (void)n_in; (void)out_size; (void)ws_size;
    const float* x    = (const float*)d_in[0];
    const float* nuc  = (const float*)d_in[1];
    const float* v0w  = (const float*)d_in[2];
    const float* v0b  = (const float*)d_in[3];
    const float* vw   = (const float*)d_in[4];
    const float* vb   = (const float*)d_in[5];
    const float* w0w  = (const float*)d_in[6];
    const float* w0b  = (const float*)d_in[7];
    const float* ww   = (const float*)d_in[8];
    const float* wb   = (const float*)d_in[9];
    const float* envw = (const float*)d_in[10];
    const float* envg = (const float*)d_in[11];
    const float* sig  = (const float*)d_in[12];
    const float* pii  = (const float*)d_in[13];
    float* out = (float*)d_out;
    u16* wsB = (u16*)d_ws;

    k_prep_main<<<638976 / 256, 256, 0, stream>>>(vw, wsB + MB_HI, wsB + MB_LO);
    k_prep_l0  <<<16384 / 256, 256, 0, stream>>>(v0w, wsB + L0_HI, wsB + L0_LO);
    k_prep_env <<<32768 / 256, 256, 0, stream>>>(envw, wsB + ENV_HI, wsB + ENV_LO);
    k_prep_two <<<4096 / 256, 256, 0, stream>>>(w0w, ww, wsB + TWOB_HI, wsB + TWOB_LO);

    const int B = in_sizes[0] / 48;
    ferminet_kernel<<<B, 256, 0, stream>>>(x, nuc, v0b, vb, w0b, wb,
                                           envg, sig, pii, wsB, out);
}

// Round 7
// 575.532 us; speedup vs baseline: 1.2439x; 1.2439x over previous
//
#include <hip/hip_runtime.h>
#include <cmath>

namespace {

typedef unsigned short u16;
typedef unsigned int u32;
using short8  = __attribute__((ext_vector_type(8))) short;
using float4v = __attribute__((ext_vector_type(4))) float;

// ---- ws layout (u16 units) ----
constexpr size_t MB_HI   = 0;                      // [3][26][16][64][8]
constexpr size_t MB_LO   = 638976;
constexpr size_t L0_HI   = 1277952;                // [2][16][64][8]
constexpr size_t L0_LO   = L0_HI + 16384;
constexpr size_t ENV_HI  = L0_LO + 16384;          // [8][8][64][8]
constexpr size_t ENV_LO  = ENV_HI + 32768;
constexpr size_t TWOB_HI = ENV_LO + 32768;         // [4][2][64][8]
constexpr size_t TWOB_LO = TWOB_HI + 4096;

__device__ __forceinline__ u16 f2bf(float f) {
    u32 u = __float_as_uint(f);
    u += 0x7FFFu + ((u >> 16) & 1u);
    return (u16)(u >> 16);
}
__device__ __forceinline__ float bf2f(u16 h) {
    return __uint_as_float(((u32)h) << 16);
}
__device__ __forceinline__ float fast_tanh(float x) {
    float e = __expf(-2.f * fabsf(x));
    float t = (1.f - e) * __builtin_amdgcn_rcpf(1.f + e);
    return copysignf(t, x);
}

// ---------------- prep kernels: weights -> bf16 hi/lo MFMA B-fragments ----------------
__global__ void k_prep_main(const float* __restrict__ vw, u16* __restrict__ hi, u16* __restrict__ lo) {
    int id = blockIdx.x * 256 + threadIdx.x;          // 3*26*16*512
    int l = id / 212992, rem = id % 212992;
    int ks = rem >> 13;
    int r2 = rem & 8191;
    int nt = r2 >> 9, lane = (r2 >> 3) & 63, j = r2 & 7;
    int n = nt * 16 + (lane & 15);
    int f = ks * 32 + ((lane >> 4) << 3) + j;
    float w = vw[(size_t)(l * 256 + n) * 832 + f];
    u16 h = f2bf(w);
    hi[id] = h; lo[id] = f2bf(w - bf2f(h));
}
__global__ void k_prep_l0(const float* __restrict__ v0w, u16* __restrict__ hi, u16* __restrict__ lo) {
    int id = blockIdx.x * 256 + threadIdx.x;          // 2*16*512
    int ks = id >> 13;
    int r2 = id & 8191;
    int nt = r2 >> 9, lane = (r2 >> 3) & 63, j = r2 & 7;
    int n = nt * 16 + (lane & 15);
    int f = ks * 32 + ((lane >> 4) << 3) + j;
    float w = (f < 56) ? v0w[n * 56 + f] : 0.f;
    u16 h = f2bf(w);
    hi[id] = h; lo[id] = f2bf(w - bf2f(h));
}
__global__ void k_prep_env(const float* __restrict__ ew, u16* __restrict__ hi, u16* __restrict__ lo) {
    int id = blockIdx.x * 256 + threadIdx.x;          // 8*8*512
    int ks = id >> 12;
    int r2 = id & 4095;
    int nt = r2 >> 9, lane = (r2 >> 3) & 63, j = r2 & 7;
    int n = nt * 16 + (lane & 15);
    int f = ks * 32 + ((lane >> 4) << 3) + j;
    float w = ew[(size_t)(((n >> 3) * 16) + (n & 7)) * 256 + f];
    u16 h = f2bf(w);
    hi[id] = h; lo[id] = f2bf(w - bf2f(h));
}
// two-stream weights: [layer][nt][lane][j]; B[k][n]=Ww[n][k]; layer0 K padded 4->32
__global__ void k_prep_two(const float* __restrict__ w0w, const float* __restrict__ ww,
                           u16* __restrict__ hi, u16* __restrict__ lo) {
    int id = blockIdx.x * 256 + threadIdx.x;          // 4*2*512 = 4096
    int l = id >> 10, r = id & 1023;
    int nt = r >> 9, lane = (r >> 3) & 63, j = r & 7;
    int n = nt * 16 + (lane & 15);
    int f = ((lane >> 4) << 3) + j;
    float w;
    if (l == 0) w = (f < 4) ? w0w[n * 4 + f] : 0.f;
    else        w = ww[(size_t)(((l - 1) * 32) + n) * 32 + f];
    u16 h = f2bf(w);
    hi[id] = h; lo[id] = f2bf(w - bf2f(h));
}

// ---------------- fused per-walker layer ----------------
// one-GEMM K-layout: [0,256) one | [256,512) g1u | [512,768) g1d | [768,800) g2u | [800,832) g2d
template <bool L0, bool RES, bool LAST>
__device__ __forceinline__ void layer_run(
    int t, float (&prev)[4][4], short8 (&twoA)[2][4],
    u16 (*stateF)[32][16][8], u16 (*g2F)[8][16][8], u16 (*g1F)[2][8][4][8],
    float (*twoS)[36],                               // this wave's 16x36 scratch
    const u16* __restrict__ Bhi, const u16* __restrict__ Blo,
    const u16* __restrict__ TBhi, const u16* __restrict__ TBlo,
    const float* __restrict__ bvp, const float* __restrict__ bwp)
{
    const int lane = t & 63, wv = t >> 6, quad = lane >> 4, l16 = lane & 15;
    float4v acc[4];
    #pragma unroll
    for (int q = 0; q < 4; ++q) acc[q] = (float4v){0.f, 0.f, 0.f, 0.f};

    const size_t wb0 = (size_t)(wv * 4) * 512 + (size_t)lane * 8;

    auto mfma_step = [&](int ks, short8 Ah, short8 Al) {
        const u16* bh = Bhi + wb0 + (size_t)ks * 8192;
        const u16* bl = Blo + wb0 + (size_t)ks * 8192;
        #pragma unroll
        for (int q = 0; q < 4; ++q) {
            short8 Wh = *(const short8*)(bh + q * 512);
            short8 Wl = *(const short8*)(bl + q * 512);
            acc[q] = __builtin_amdgcn_mfma_f32_16x16x32_bf16(Ah, Wh, acc[q], 0, 0, 0);
            acc[q] = __builtin_amdgcn_mfma_f32_16x16x32_bf16(Al, Wh, acc[q], 0, 0, 0);
            acc[q] = __builtin_amdgcn_mfma_f32_16x16x32_bf16(Ah, Wl, acc[q], 0, 0, 0);
        }
    };

    if (L0) {
        #pragma unroll
        for (int ks = 0; ks < 2; ++ks) {
            short8 Ah = *(const short8*)&g2F[0][ks * 4 + quad][l16][0];
            short8 Al = *(const short8*)&g2F[1][ks * 4 + quad][l16][0];
            mfma_step(ks, Ah, Al);
        }
    } else {
        #pragma unroll 2
        for (int ks = 0; ks < 8; ++ks) {        // one-part from state frags
            short8 Ah = *(const short8*)&stateF[0][ks * 4 + quad][l16][0];
            short8 Al = *(const short8*)&stateF[1][ks * 4 + quad][l16][0];
            mfma_step(ks, Ah, Al);
        }
        #pragma unroll 2
        for (int ks = 8; ks < 24; ++ks) {       // g1-part: broadcast frags from LDS
            const int ud = (ks < 16) ? 0 : 1;
            const int kg = (ks - 8) & 7;
            short8 Ah = *(const short8*)&g1F[0][ud][kg][quad][0];
            short8 Al = *(const short8*)&g1F[1][ud][kg][quad][0];
            mfma_step(ks, Ah, Al);
        }
        #pragma unroll
        for (int ks = 24; ks < 26; ++ks) {      // g2-part
            short8 Ah = *(const short8*)&g2F[0][(ks - 24) * 4 + quad][l16][0];
            short8 Al = *(const short8*)&g2F[1][(ks - 24) * 4 + quad][l16][0];
            mfma_step(ks, Ah, Al);
        }
    }
    __syncthreads();   // all LDS A-source reads complete

    // ---- epilogue-one: bias+tanh+residual (regs), g1 means -> g1F, state frags ----
    #pragma unroll
    for (int q = 0; q < 4; ++q) {
        const int n = (wv * 4 + q) * 16 + l16;
        const float bvv = bvp[n];
        #pragma unroll
        for (int r = 0; r < 4; ++r) {
            float v = fast_tanh(acc[q][r] + bvv);
            if (RES) v += prev[q][r];
            prev[q][r] = v;
        }
        if (!LAST) {
            float su = 0.f, sd = 0.f;
            #pragma unroll
            for (int r = 0; r < 4; ++r) { if (quad < 2) su += prev[q][r]; else sd += prev[q][r]; }
            su += __shfl_xor(su, 16); su += __shfl_xor(su, 32);
            sd += __shfl_xor(sd, 16); sd += __shfl_xor(sd, 32);
            if (quad == 0) {
                const int kg = n >> 5, qd = (n >> 3) & 3, jj = n & 7;
                float mu = su * 0.125f, md = sd * 0.125f;
                u16 hu = f2bf(mu), hd = f2bf(md);
                g1F[0][0][kg][qd][jj] = hu; g1F[1][0][kg][qd][jj] = f2bf(mu - bf2f(hu));
                g1F[0][1][kg][qd][jj] = hd; g1F[1][1][kg][qd][jj] = f2bf(md - bf2f(hd));
            }
        }
        const int ko = n >> 3, jj = n & 7;
        #pragma unroll
        for (int r = 0; r < 4; ++r) {
            const int m = quad * 4 + r;
            u16 h = f2bf(prev[q][r]);
            stateF[0][ko][m][jj] = h;
            stateF[1][ko][m][jj] = f2bf(prev[q][r] - bf2f(h));
        }
    }

    // ---- two-stream GEMM + epilogue, per-mt (short tac live range, acc dead) ----
    if (!LAST) {
        short8 TWh[2], TWl[2];
        #pragma unroll
        for (int nt = 0; nt < 2; ++nt) {
            TWh[nt] = *(const short8*)(TBhi + nt * 512 + (size_t)lane * 8);
            TWl[nt] = *(const short8*)(TBlo + nt * 512 + (size_t)lane * 8);
        }
        #pragma unroll
        for (int mt = 0; mt < 4; ++mt) {
            const int it = wv * 4 + mt;
            float4v tac[2];
            tac[0] = (float4v){0.f, 0.f, 0.f, 0.f};
            tac[1] = (float4v){0.f, 0.f, 0.f, 0.f};
            #pragma unroll
            for (int nt = 0; nt < 2; ++nt) {
                tac[nt] = __builtin_amdgcn_mfma_f32_16x16x32_bf16(twoA[0][mt], TWh[nt], tac[nt], 0, 0, 0);
                tac[nt] = __builtin_amdgcn_mfma_f32_16x16x32_bf16(twoA[1][mt], TWh[nt], tac[nt], 0, 0, 0);
                tac[nt] = __builtin_amdgcn_mfma_f32_16x16x32_bf16(twoA[0][mt], TWl[nt], tac[nt], 0, 0, 0);
            }
            #pragma unroll
            for (int nt = 0; nt < 2; ++nt) {
                const int c = nt * 16 + l16;
                const float bwv = bwp[c];
                #pragma unroll
                for (int r = 0; r < 4; ++r)
                    twoS[quad * 4 + r][c] = fast_tanh(tac[nt][r] + bwv);
            }
            // A-layout read: row l16, channels quad*8..+7 (wave-private, in-order LDS)
            float4 ra = *(const float4*)&twoS[l16][quad * 8];
            float4 rb = *(const float4*)&twoS[l16][quad * 8 + 4];
            float nv[8] = {ra.x, ra.y, ra.z, ra.w, rb.x, rb.y, rb.z, rb.w};
            #pragma unroll
            for (int j2 = 0; j2 < 8; ++j2) {
                float v = nv[j2];
                if (RES) v += bf2f((u16)twoA[0][mt][j2]) + bf2f((u16)twoA[1][mt][j2]);
                nv[j2] = v;
                u16 h = f2bf(v);
                twoA[0][mt][j2] = (short)h;
                twoA[1][mt][j2] = (short)f2bf(v - bf2f(h));
            }
            // g2 means: reduce over pairs (l16 octets)
            #pragma unroll
            for (int j2 = 0; j2 < 8; ++j2) {
                float s = nv[j2];
                s += __shfl_xor(s, 1); s += __shfl_xor(s, 2); s += __shfl_xor(s, 4);
                nv[j2] = s * 0.125f;
            }
            if (l16 == 0 || l16 == 8) {
                const int base = (l16 == 0) ? 0 : 4;
                #pragma unroll
                for (int j2 = 0; j2 < 8; ++j2) {
                    u16 h = f2bf(nv[j2]);
                    g2F[0][base + quad][it][j2] = h;
                    g2F[1][base + quad][it][j2] = f2bf(nv[j2] - bf2f(h));
                }
            }
        }
    }
    __syncthreads();
}

__global__ __launch_bounds__(256, 4) void ferminet_kernel(
    const float* __restrict__ x,
    const float* __restrict__ nuc,
    const float* __restrict__ v0_b,
    const float* __restrict__ v_b,
    const float* __restrict__ w0_b,
    const float* __restrict__ w_b,
    const float* __restrict__ env_g,
    const float* __restrict__ sigma,
    const float* __restrict__ pi_,
    const u16* __restrict__ wsB,
    float* __restrict__ out)
{
    __shared__ u16  stateF[2][32][16][8];   // 16 KB; psi aliases after layers
    __shared__ u16  g2F[2][8][16][8];       // 4 KB; l0 one-A aliases
    __shared__ u16  g1F[2][2][8][4][8];     // 2 KB
    __shared__ float twoS[4][16][36];       // 9 KB per-wave transpose scratch
    __shared__ float xs[48];
    __shared__ float rs[64];
    __shared__ float dets[2][16];
    float* psi = (float*)&stateF[0][0][0][0];   // [2][16][8][8] fp32

    const int t = threadIdx.x;
    const int b = blockIdx.x;
    const int lane = t & 63, wv = t >> 6, quad = lane >> 4, l16 = lane & 15;

    if (t < 48) xs[t] = x[(size_t)b * 48 + t];
    // zero l0A pad octet (koct 7: k 56..63)
    if (t >= 128 && t < 192) ((u32*)&g2F[0][7][0][0])[t - 128] = 0u;
    if (t >= 192 && t < 256) ((u32*)&g2F[1][7][0][0])[t - 192] = 0u;
    __syncthreads();

    // ---- init: one0 features + r + g1u0/g1d0 (threads 0..63) ----
    if (t < 64) {
        int n = t >> 2, m = t & 3;
        float ox = xs[n * 3 + 0] - nuc[m * 3 + 0];
        float oy = xs[n * 3 + 1] - nuc[m * 3 + 1];
        float oz = xs[n * 3 + 2] - nuc[m * 3 + 2];
        float d = sqrtf(ox * ox + oy * oy + oz * oz);
        rs[n * 4 + m] = d;
        float v[4] = {ox, oy, oz, d};
        #pragma unroll
        for (int c = 0; c < 4; ++c) {
            int k = m * 4 + c;
            u16 h = f2bf(v[c]);
            g2F[0][k >> 3][n][k & 7] = h;
            g2F[1][k >> 3][n][k & 7] = f2bf(v[c] - bf2f(h));
        }
        #pragma unroll
        for (int c = 0; c < 4; ++c) {
            float s = v[c];
            s += __shfl_xor(s, 4); s += __shfl_xor(s, 8); s += __shfl_xor(s, 16);
            if ((n & 7) == 0) {
                float mn = s * 0.125f;
                int k = 16 + (n >> 3) * 16 + m * 4 + c;
                u16 h = f2bf(mn);
                u16 lo = f2bf(mn - bf2f(h));
                #pragma unroll
                for (int mm = 0; mm < 16; ++mm) {
                    g2F[0][k >> 3][mm][k & 7] = h;
                    g2F[1][k >> 3][mm][k & 7] = lo;
                }
            }
        }
    }
    // ---- init: g2u0/g2d0 means for l0A (threads 0..127: t = i*8 + ud*4 + c) ----
    if (t < 128) {
        int i = t >> 3, ud = (t >> 2) & 1, c = t & 3;
        float s = 0.f;
        #pragma unroll
        for (int jo = 0; jo < 8; ++jo) {
            int j = ud * 8 + jo;
            float dx = xs[j * 3 + 0] - xs[i * 3 + 0];
            float dy = xs[j * 3 + 1] - xs[i * 3 + 1];
            float dz = xs[j * 3 + 2] - xs[i * 3 + 2];
            float v;
            if (c == 0) v = dx;
            else if (c == 1) v = dy;
            else if (c == 2) v = dz;
            else { float s2 = dx * dx + dy * dy + dz * dz; v = (s2 > 0.f) ? sqrtf(s2) : 0.f; }
            s += v;
        }
        float mn = s * 0.125f;
        int k = 48 + ud * 4 + c;
        u16 h = f2bf(mn);
        g2F[0][6][i][k & 7] = h;
        g2F[1][6][i][k & 7] = f2bf(mn - bf2f(h));
    }
    // ---- init two0 A-fragments in registers: lane (quad,l16) <- pair (it, l16) ----
    short8 twoA[2][4];
    {
        short8 z8 = {0, 0, 0, 0, 0, 0, 0, 0};
        #pragma unroll
        for (int mt = 0; mt < 4; ++mt) { twoA[0][mt] = z8; twoA[1][mt] = z8; }
        if (quad == 0) {
            #pragma unroll
            for (int mt = 0; mt < 4; ++mt) {
                const int it = wv * 4 + mt;
                float dx = xs[l16 * 3 + 0] - xs[it * 3 + 0];
                float dy = xs[l16 * 3 + 1] - xs[it * 3 + 1];
                float dz = xs[l16 * 3 + 2] - xs[it * 3 + 2];
                float s2 = dx * dx + dy * dy + dz * dz;
                float nr = (s2 > 0.f) ? sqrtf(s2) : 0.f;
                float v[4] = {dx, dy, dz, nr};
                #pragma unroll
                for (int c = 0; c < 4; ++c) {
                    u16 h = f2bf(v[c]);
                    twoA[0][mt][c] = (short)h;
                    twoA[1][mt][c] = (short)f2bf(v[c] - bf2f(h));
                }
            }
        }
    }
    __syncthreads();

    // ---- 4 layers ----
    float prev[4][4];
    layer_run<true,  false, false>(t, prev, twoA, stateF, g2F, g1F, twoS[wv],
        wsB + L0_HI, wsB + L0_LO, wsB + TWOB_HI, wsB + TWOB_LO, v0_b, w0_b);
    layer_run<false, true,  false>(t, prev, twoA, stateF, g2F, g1F, twoS[wv],
        wsB + MB_HI + 0 * 212992, wsB + MB_LO + 0 * 212992,
        wsB + TWOB_HI + 1024, wsB + TWOB_LO + 1024, v_b + 0 * 256, w_b + 0 * 32);
    layer_run<false, true,  false>(t, prev, twoA, stateF, g2F, g1F, twoS[wv],
        wsB + MB_HI + 1 * 212992, wsB + MB_LO + 1 * 212992,
        wsB + TWOB_HI + 2048, wsB + TWOB_LO + 2048, v_b + 1 * 256, w_b + 1 * 32);
    layer_run<false, true,  true >(t, prev, twoA, stateF, g2F, g1F, twoS[wv],
        wsB + MB_HI + 2 * 212992, wsB + MB_LO + 2 * 212992,
        wsB + TWOB_HI + 3072, wsB + TWOB_LO + 3072, v_b + 2 * 256, w_b + 2 * 32);

    // ---- envelope GEMM: K=256, N=128 (wave -> 2 ntiles) ----
    {
        float4v ac2[2];
        ac2[0] = (float4v){0.f, 0.f, 0.f, 0.f};
        ac2[1] = (float4v){0.f, 0.f, 0.f, 0.f};
        const size_t wb0 = (size_t)(wv * 2) * 512 + (size_t)lane * 8;
        const u16* Eh = wsB + ENV_HI;
        const u16* El = wsB + ENV_LO;
        #pragma unroll 2
        for (int ks = 0; ks < 8; ++ks) {
            short8 Ah = *(const short8*)&stateF[0][ks * 4 + quad][l16][0];
            short8 Al = *(const short8*)&stateF[1][ks * 4 + quad][l16][0];
            const u16* bh = Eh + wb0 + (size_t)ks * 4096;
            const u16* bl = El + wb0 + (size_t)ks * 4096;
            #pragma unroll
            for (int q = 0; q < 2; ++q) {
                short8 Wh = *(const short8*)(bh + q * 512);
                short8 Wl = *(const short8*)(bl + q * 512);
                ac2[q] = __builtin_amdgcn_mfma_f32_16x16x32_bf16(Ah, Wh, ac2[q], 0, 0, 0);
                ac2[q] = __builtin_amdgcn_mfma_f32_16x16x32_bf16(Al, Wh, ac2[q], 0, 0, 0);
                ac2[q] = __builtin_amdgcn_mfma_f32_16x16x32_bf16(Ah, Wl, ac2[q], 0, 0, 0);
            }
        }
        float vals[2][4];
        int kk[2], ii[2];
        #pragma unroll
        for (int q = 0; q < 2; ++q) {
            const int n = (wv * 2 + q) * 16 + l16;
            const int k = n >> 3, i = n & 7, kif = k * 16 + i;
            kk[q] = k; ii[q] = i;
            const float lc = 256.f * env_g[kif];
            const float4 pw4 = *(const float4*)&pi_[(size_t)kif * 4];
            const float4 sg4 = *(const float4*)&sigma[(size_t)kif * 4];
            const float sg[4] = {fabsf(sg4.x), fabsf(sg4.y), fabsf(sg4.z), fabsf(sg4.w)};
            const float pw[4] = {pw4.x, pw4.y, pw4.z, pw4.w};
            #pragma unroll
            for (int r = 0; r < 4; ++r) {
                const int je = quad * 4 + r;
                float E = 0.f;
                #pragma unroll
                for (int m = 0; m < 4; ++m) E += pw[m] * __expf(-sg[m] * rs[je * 4 + m]);
                vals[q][r] = (ac2[q][r] + lc) * E;
            }
        }
        __syncthreads();   // state-frag reads complete before psi overwrite
        #pragma unroll
        for (int q = 0; q < 2; ++q) {
            #pragma unroll
            for (int r = 0; r < 4; ++r) {
                const int je = quad * 4 + r;
                const int s = je >> 3, j = je & 7;
                psi[((s * 16 + kk[q]) * 8 + ii[q]) * 8 + j] = vals[q][r];
            }
        }
    }
    __syncthreads();

    // ---- 32 8x8 determinants ----
    if (t < 32) {
        int s = t >> 4, k = t & 15;
        const float* src = psi + (s * 16 + k) * 64;
        float m[8][8];
        #pragma unroll
        for (int i = 0; i < 8; ++i)
            #pragma unroll
            for (int j = 0; j < 8; ++j) m[i][j] = src[i * 8 + j];
        float det = 1.f;
        #pragma unroll
        for (int c = 0; c < 8; ++c) {
            #pragma unroll
            for (int r = c + 1; r < 8; ++r) {
                if (fabsf(m[r][c]) > fabsf(m[c][c])) {
                    det = -det;
                    #pragma unroll
                    for (int j = 0; j < 8; ++j) {
                        float tmp = m[c][j]; m[c][j] = m[r][j]; m[r][j] = tmp;
                    }
                }
            }
            float piv = m[c][c];
            det *= piv;
            if (piv != 0.f) {
                float inv = 1.f / piv;
                #pragma unroll
                for (int r = c + 1; r < 8; ++r) {
                    float fac = m[r][c] * inv;
                    #pragma unroll
                    for (int j = c; j < 8; ++j) m[r][j] -= fac * m[c][j];
                }
            }
        }
        dets[s][k] = det;
    }
    __syncthreads();

    if (t == 0) {
        float s = 0.f;
        #pragma unroll
        for (int k = 0; k < 16; ++k) s += dets[0][k] * dets[1][k];
        out[b] = s;
    }
}

} // namespace

extern "C" void kernel_launch(void* const* d_in, const int* in_sizes, int n_in,
                              void* d_out, int out_size, void* d_ws, size_t ws_size,
                              hipStream_t stream) {
    (void)n_in; (void)out_size; (void)ws_size;
    const float* x    = (const float*)d_in[0];
    const float* nuc  = (const float*)d_in[1];
    const float* v0w  = (const float*)d_in[2];
    const float* v0b  = (const float*)d_in[3];
    const float* vw   = (const float*)d_in[4];
    const float* vb   = (const float*)d_in[5];
    const float* w0w  = (const float*)d_in[6];
    const float* w0b  = (const float*)d_in[7];
    const float* ww   = (const float*)d_in[8];
    const float* wb   = (const float*)d_in[9];
    const float* envw = (const float*)d_in[10];
    const float* envg = (const float*)d_in[11];
    const float* sig  = (const float*)d_in[12];
    const float* pii  = (const float*)d_in[13];
    float* out = (float*)d_out;
    u16* wsB = (u16*)d_ws;

    k_prep_main<<<638976 / 256, 256, 0, stream>>>(vw, wsB + MB_HI, wsB + MB_LO);
    k_prep_l0  <<<16384 / 256, 256, 0, stream>>>(v0w, wsB + L0_HI, wsB + L0_LO);
    k_prep_env <<<32768 / 256, 256, 0, stream>>>(envw, wsB + ENV_HI, wsB + ENV_LO);
    k_prep_two <<<4096 / 256, 256, 0, stream>>>(w0w, ww, wsB + TWOB_HI, wsB + TWOB_LO);

    const int B = in_sizes[0] / 48;
    ferminet_kernel<<<B, 256, 0, stream>>>(x, nuc, v0b, vb, w0b, wb,
                                           envg, sig, pii, wsB, out);
}